// Round 1
// baseline (306.602 us; speedup 1.0000x reference)
//
#include <hip/hip_runtime.h>

// LocalAttention: conv_in(64->192) -> unfold/attn/fold over T*9 -> conv_out -> BN3d -> residual
// Collapsed form: folded[c,t,Y] = (1/36) sum_{c'} theta[c',t,Y] * sum_d cnt(d,Y) sum_r phi[c',r,Y+d]*g[c,r,Y+d]
// ws usage: theta/phi/g/preBN (bf16, 12.85 MB each) + 128 f32 stats = ~51.4 MB total.

typedef unsigned short u16;
typedef unsigned int u32;

#define BB 8
#define TT 4
#define HH 56
#define HWD 3136          // 56*56
#define NPC 64            // channels / HID
#define NTOT 100352.0f    // B*T*H*W

__device__ __forceinline__ float bf_lo(u32 u) { return __uint_as_float(u << 16); }
__device__ __forceinline__ float bf_hi(u32 u) { return __uint_as_float(u & 0xffff0000u); }
__device__ __forceinline__ float bf16u(u16 u) { return __uint_as_float(((u32)u) << 16); }
__device__ __forceinline__ u16 f2bf(float f) {
  u32 u = __float_as_uint(f);
  u32 r = (u + 0x7fffu + ((u >> 16) & 1u)) >> 16;
  return (u16)r;
}
__device__ __forceinline__ u32 pack2(float a, float b) {
  return (u32)f2bf(a) | ((u32)f2bf(b) << 16);
}
__device__ __forceinline__ int imax(int a, int b) { return a > b ? a : b; }
__device__ __forceinline__ int imin(int a, int b) { return a < b ? a : b; }
// #valid (k1,k2) tap pairs along one axis for offset d at coordinate p
__device__ __forceinline__ float cntf(int d, int p) {
  int lo = imax(-1, imax(-1 - d, p - (HH - 1)));
  int hi = imin(1, imin(1 - d, p));
  int n = hi - lo + 1;
  return n > 0 ? (float)n : 0.f;
}

// ---------------- K1: conv_in (x fp32 -> theta/phi/g bf16), also zero stats ----------------
__global__ __launch_bounds__(256) void k_conv_in(const float* __restrict__ x,
                                                 const float* __restrict__ w_in,
                                                 const float* __restrict__ b_in,
                                                 u16* __restrict__ th, u16* __restrict__ ph,
                                                 u16* __restrict__ gg, float* __restrict__ stats) {
  if (blockIdx.x == 0 && threadIdx.x < 128) stats[threadIdx.x] = 0.f;
  int bt = blockIdx.x / 13, chunk = blockIdx.x % 13;
  int b = bt >> 2, t = bt & 3;
  int pos = chunk * 256 + threadIdx.x;
  if (pos >= HWD) return;
  const float* xb = x + ((b * 256 + t) * HWD + pos);  // c-stride = 4*3136
  float xr[64];
#pragma unroll
  for (int c = 0; c < 64; ++c) xr[c] = xb[c * 12544];
  u16* outs0 = th; u16* outs1 = ph; u16* outs2 = gg;
  int obase = (bt * HWD + pos) * 64;
#pragma unroll
  for (int g = 0; g < 3; ++g) {
    const float* wg = w_in + g * 4096;
    const float* bg = b_in + g * 64;
    u16* og = (g == 0 ? outs0 : (g == 1 ? outs1 : outs2)) + obase;
    for (int ob = 0; ob < 8; ++ob) {
      float a[8];
#pragma unroll
      for (int oj = 0; oj < 8; ++oj) {
        int o = ob * 8 + oj;
        float acc = bg[o];
#pragma unroll
        for (int c = 0; c < 64; ++c) acc += wg[o * 64 + c] * xr[c];  // w uniform -> s_load
        a[oj] = acc;
      }
      uint4 v;
      v.x = pack2(a[0], a[1]); v.y = pack2(a[2], a[3]);
      v.z = pack2(a[4], a[5]); v.w = pack2(a[6], a[7]);
      *reinterpret_cast<uint4*>(&og[ob * 8]) = v;
    }
  }
}

// ---------------- K2: fused attention + fold + conv_out, per 4x4 spatial tile ----------------
__global__ __launch_bounds__(512) void k_attn(const u16* __restrict__ th, const u16* __restrict__ ph,
                                              const u16* __restrict__ gg,
                                              const float* __restrict__ w_out,
                                              const float* __restrict__ b_out,
                                              u16* __restrict__ pre) {
  __shared__ u16 ph_s[64][4][72];   // [Z(8x8 halo)][rho][c pad 64->72]
  __shared__ u16 g_s[64][4][72];
  __shared__ u16 th_s[16][4][72];   // [pos(4x4)][tau][c]
  __shared__ float a_s[16][25][4][4];   // [pos][d][rho][tau], includes cnt/36 scale
  __shared__ float folded_s[16][4][64]; // [pos][tau][c]
  __shared__ u16 w_s[64][66];           // w_out transposed [c][o], pad 66

  int bi = blockIdx.x;
  int b = bi / 196, tile = bi % 196;
  int ty = tile / 14, tx = tile % 14;
  int y0 = ty * 4, x0 = tx * 4;
  int tid = threadIdx.x;

  // stage phi & g halo (8x8 positions, zero-filled OOB)
  for (int task = tid; task < 2048; task += 512) {
    int rho = task >> 9, rem = task & 511, Z = rem >> 3, ch = rem & 7;
    int zy = Z >> 3, zx = Z & 7;
    int Y = y0 - 2 + zy, X = x0 - 2 + zx;
    uint4 vp = make_uint4(0, 0, 0, 0), vg = make_uint4(0, 0, 0, 0);
    if (Y >= 0 && Y < HH && X >= 0 && X < HH) {
      int gi = (((b * 4 + rho) * HWD) + Y * HH + X) * 64 + ch * 8;
      vp = *reinterpret_cast<const uint4*>(&ph[gi]);
      vg = *reinterpret_cast<const uint4*>(&gg[gi]);
    }
    *reinterpret_cast<uint4*>(&ph_s[Z][rho][ch * 8]) = vp;
    *reinterpret_cast<uint4*>(&g_s[Z][rho][ch * 8]) = vg;
  }
  // stage theta tile
  {
    int tau = tid >> 7, rem = tid & 127, pos = rem >> 3, ch = rem & 7;
    int Y = y0 + (pos >> 2), X = x0 + (pos & 3);
    int gi = (((b * 4 + tau) * HWD) + Y * HH + X) * 64 + ch * 8;
    *reinterpret_cast<uint4*>(&th_s[pos][tau][ch * 8]) = *reinterpret_cast<const uint4*>(&th[gi]);
  }
  // stage w_out transposed (bf16)
  for (int task = tid; task < 4096; task += 512) {
    int o = task >> 6, c = task & 63;
    w_s[c][o] = f2bf(w_out[task]);
  }
  __syncthreads();

  // Phase A: A'[pos][d][rho][tau] = (theta(Y,tau) . phi(Y+d,rho)) * cntx*cnty/36
  {
    int pos = tid >> 5, tau = (tid >> 3) & 3, rho = (tid >> 1) & 3, dh = tid & 1;
    int py = pos >> 2, px = pos & 3;
    float tr[64];
    const uint4* tp = reinterpret_cast<const uint4*>(&th_s[pos][tau][0]);
#pragma unroll
    for (int k = 0; k < 8; ++k) {
      uint4 v = tp[k];
      tr[k * 8 + 0] = bf_lo(v.x); tr[k * 8 + 1] = bf_hi(v.x);
      tr[k * 8 + 2] = bf_lo(v.y); tr[k * 8 + 3] = bf_hi(v.y);
      tr[k * 8 + 4] = bf_lo(v.z); tr[k * 8 + 5] = bf_hi(v.z);
      tr[k * 8 + 6] = bf_lo(v.w); tr[k * 8 + 7] = bf_hi(v.w);
    }
    for (int dd = dh; dd < 25; dd += 2) {
      int q = dd / 5;
      int dy = q - 2, dx = dd - q * 5 - 2;
      int Z = (py + 2 + dy) * 8 + (px + 2 + dx);
      const uint4* pp = reinterpret_cast<const uint4*>(&ph_s[Z][rho][0]);
      float a0 = 0.f, a1 = 0.f, a2 = 0.f, a3 = 0.f;
#pragma unroll
      for (int k = 0; k < 8; ++k) {
        uint4 v = pp[k];
        a0 += bf_lo(v.x) * tr[k * 8 + 0]; a1 += bf_hi(v.x) * tr[k * 8 + 1];
        a2 += bf_lo(v.y) * tr[k * 8 + 2]; a3 += bf_hi(v.y) * tr[k * 8 + 3];
        a0 += bf_lo(v.z) * tr[k * 8 + 4]; a1 += bf_hi(v.z) * tr[k * 8 + 5];
        a2 += bf_lo(v.w) * tr[k * 8 + 6]; a3 += bf_hi(v.w) * tr[k * 8 + 7];
      }
      float acc = (a0 + a1) + (a2 + a3);
      float sc = cntf(dy, y0 + py) * cntf(dx, x0 + px) * (1.f / 36.f);
      a_s[pos][dd][rho][tau] = acc * sc;
    }
  }
  __syncthreads();

  // Phase B: folded[pos][tau][c] = sum_{d,rho} A' * g[c,rho,Y+d]
  {
    int pos = tid >> 5, cg = tid & 31, c2 = cg * 2;
    int py = pos >> 2, px = pos & 3;
    float f0[4] = {0, 0, 0, 0}, f1[4] = {0, 0, 0, 0};
    for (int dd = 0; dd < 25; ++dd) {
      int q = dd / 5;
      int dy = q - 2, dx = dd - q * 5 - 2;
      int Z = (py + 2 + dy) * 8 + (px + 2 + dx);
#pragma unroll
      for (int r = 0; r < 4; ++r) {
        float4 a4 = *reinterpret_cast<const float4*>(&a_s[pos][dd][r][0]);
        u32 gv = *reinterpret_cast<const u32*>(&g_s[Z][r][c2]);
        float ga = bf_lo(gv), gb = bf_hi(gv);
        f0[0] += ga * a4.x; f0[1] += ga * a4.y; f0[2] += ga * a4.z; f0[3] += ga * a4.w;
        f1[0] += gb * a4.x; f1[1] += gb * a4.y; f1[2] += gb * a4.z; f1[3] += gb * a4.w;
      }
    }
#pragma unroll
    for (int t = 0; t < 4; ++t) {
      folded_s[pos][t][c2] = f0[t];
      folded_s[pos][t][c2 + 1] = f1[t];
    }
  }
  __syncthreads();

  // Phase C: preBN[o,tau] = w_out . folded + b_out ; store bf16 [b][tau][hw][o]
  {
    int pos = tid >> 5, og = tid & 31, o2 = og * 2;
    float a0[4] = {0, 0, 0, 0}, a1[4] = {0, 0, 0, 0};
    for (int c = 0; c < 64; ++c) {
      u32 wv = *reinterpret_cast<const u32*>(&w_s[c][o2]);
      float w0 = bf_lo(wv), w1 = bf_hi(wv);
#pragma unroll
      for (int t = 0; t < 4; ++t) {
        float fv = folded_s[pos][t][c];
        a0[t] += w0 * fv; a1[t] += w1 * fv;
      }
    }
    float bo0 = b_out[o2], bo1 = b_out[o2 + 1];
    int hw = (y0 + (pos >> 2)) * HH + x0 + (pos & 3);
#pragma unroll
    for (int t = 0; t < 4; ++t) {
      u32 pv = pack2(a0[t] + bo0, a1[t] + bo1);
      *reinterpret_cast<u32*>(&pre[(((b * 4 + t) * HWD) + hw) * 64 + o2]) = pv;
    }
  }
}

// ---------------- K3: per-channel sum / sumsq of preBN ----------------
__global__ __launch_bounds__(256) void k_stats(const u16* __restrict__ pre, float* __restrict__ stats) {
  __shared__ float rs[2][4][64];
  int tid = threadIdx.x;
  int o = tid & 63, pg = tid >> 6;
  int base = blockIdx.x * 1024;
  float s = 0.f, q = 0.f;
  for (int j = 0; j < 256; ++j) {
    int P = base + pg + j * 4;
    float v = bf16u(pre[P * 64 + o]);
    s += v; q += v * v;
  }
  rs[0][pg][o] = s; rs[1][pg][o] = q;
  __syncthreads();
  if (tid < 64) {
    float ts = rs[0][0][tid] + rs[0][1][tid] + rs[0][2][tid] + rs[0][3][tid];
    float tq = rs[1][0][tid] + rs[1][1][tid] + rs[1][2][tid] + rs[1][3][tid];
    atomicAdd(&stats[tid], ts);
    atomicAdd(&stats[64 + tid], tq);
  }
}

// ---------------- K4: BN finalize + residual ----------------
__global__ __launch_bounds__(256) void k_final(const float* __restrict__ x, const u16* __restrict__ pre,
                                               const float* __restrict__ stats,
                                               const float* __restrict__ gamma,
                                               const float* __restrict__ beta,
                                               float* __restrict__ out) {
  __shared__ u16 pre_s[64][66];  // pad 66 -> stride 33 words: 2-way free
  int bi = blockIdx.x;
  int bt = bi / 49, ck = bi % 49;
  int b = bt >> 2, t = bt & 3;
  int hw0 = ck * 64;
  int tid = threadIdx.x;
  const u32* src = reinterpret_cast<const u32*>(pre) + (bt * HWD + hw0) * 32;
  for (int task = tid; task < 2048; task += 256) {
    int p = task >> 5, cu = task & 31;
    *reinterpret_cast<u32*>(&pre_s[p][cu * 2]) = src[p * 32 + cu];
  }
  __syncthreads();
  int cg = tid >> 6, pl = tid & 63;
  int hw = hw0 + pl;
  const float invN = 1.f / NTOT;
  for (int i = 0; i < 16; ++i) {
    int c = cg * 16 + i;
    float mu = stats[c] * invN;
    float var = stats[64 + c] * invN - mu * mu;
    float scv = rsqrtf(var + 1e-5f) * gamma[c];
    float sh = beta[c] - mu * scv;
    float v = bf16u(pre_s[pl][c]);
    int oi = ((b * 64 + c) * 4 + t) * HWD + hw;
    out[oi] = x[oi] + v * scv + sh;
  }
}

extern "C" void kernel_launch(void* const* d_in, const int* in_sizes, int n_in,
                              void* d_out, int out_size, void* d_ws, size_t ws_size,
                              hipStream_t stream) {
  const float* x = (const float*)d_in[0];
  const float* w_in = (const float*)d_in[1];
  const float* b_in = (const float*)d_in[2];
  const float* w_out = (const float*)d_in[3];
  const float* b_out = (const float*)d_in[4];
  const float* gamma = (const float*)d_in[5];
  const float* beta = (const float*)d_in[6];
  float* out = (float*)d_out;

  const size_t NE = (size_t)BB * TT * HWD * 64;  // 6,422,528 elements per bf16 tensor
  u16* th = (u16*)d_ws;
  u16* ph = th + NE;
  u16* gg = ph + NE;
  u16* pre = gg + NE;
  float* stats = (float*)((char*)d_ws + 4 * NE * sizeof(u16));  // 128 floats

  k_conv_in<<<dim3(BB * TT * 13), dim3(256), 0, stream>>>(x, w_in, b_in, th, ph, gg, stats);
  k_attn<<<dim3(BB * 196), dim3(512), 0, stream>>>(th, ph, gg, w_out, b_out, pre);
  k_stats<<<dim3(98), dim3(256), 0, stream>>>(pre, stats);
  k_final<<<dim3(BB * TT * 49), dim3(256), 0, stream>>>(x, pre, stats, gamma, beta, out);
}

// Round 2
// 201.129 us; speedup vs baseline: 1.5244x; 1.5244x over previous
//
#include <hip/hip_runtime.h>

// LocalAttention: conv_in(64->192) -> unfold/attn/fold over T*9 -> conv_out -> BN3d -> residual
// Collapsed form: folded[c,t,Y] = (1/36) sum_{c'} theta[c',t,Y] * sum_d cnt(d,Y) sum_r phi[c',r,Y+d]*g[c,r,Y+d]
// ws usage: theta/phi/g/preBN (bf16, 12.85 MB each) + 128 f32 stats = ~51.4 MB total.

typedef unsigned short u16;
typedef unsigned int u32;

#define BB 8
#define TT 4
#define HH 56
#define HWD 3136          // 56*56
#define NPC 64            // channels / HID
#define NTOT 100352.0f    // B*T*H*W

__device__ __forceinline__ float bf_lo(u32 u) { return __uint_as_float(u << 16); }
__device__ __forceinline__ float bf_hi(u32 u) { return __uint_as_float(u & 0xffff0000u); }
__device__ __forceinline__ float bf16u(u16 u) { return __uint_as_float(((u32)u) << 16); }
__device__ __forceinline__ u16 f2bf(float f) {
  u32 u = __float_as_uint(f);
  u32 r = (u + 0x7fffu + ((u >> 16) & 1u)) >> 16;
  return (u16)r;
}
__device__ __forceinline__ u32 pack2(float a, float b) {
  return (u32)f2bf(a) | ((u32)f2bf(b) << 16);
}
__device__ __forceinline__ int imax(int a, int b) { return a > b ? a : b; }
__device__ __forceinline__ int imin(int a, int b) { return a < b ? a : b; }
// #valid (k1,k2) tap pairs along one axis for offset d at coordinate p
__device__ __forceinline__ float cntf(int d, int p) {
  int lo = imax(-1, imax(-1 - d, p - (HH - 1)));
  int hi = imin(1, imin(1 - d, p));
  int n = hi - lo + 1;
  return n > 0 ? (float)n : 0.f;
}

// ---------------- K1: conv_in as register-tiled GEMM ----------------
// C[192 x 3136] per (b,t): W[192x64] * X[64 x ptile]; block = 64-position tile.
// Threads 16x16: oi covers outputs (4 per tensor), pi covers 4 positions.
__global__ __launch_bounds__(256) void k_conv_in(const float* __restrict__ x,
                                                 const float* __restrict__ w_in,
                                                 const float* __restrict__ b_in,
                                                 u16* __restrict__ th, u16* __restrict__ ph,
                                                 u16* __restrict__ gg, float* __restrict__ stats) {
  __shared__ float ws[64][195];  // [c][o], pad 195 -> 2-way max on all access patterns
  __shared__ float xs[64][64];   // [c][p]
  if (blockIdx.x == 0 && threadIdx.x < 128) stats[threadIdx.x] = 0.f;
  int bt = blockIdx.x / 49, chunk = blockIdx.x % 49;
  int b = bt >> 2, t = bt & 3;
  int p0 = chunk * 64;
  int tid = threadIdx.x;

  // stage w transposed: ws[c][o] = w_in[o*64+c]  (12288 elems, 48/thread)
  for (int task = tid; task < 12288; task += 256) {
    int o = task >> 6, c = task & 63;
    ws[c][o] = w_in[task];
  }
  // stage x tile: 4096 floats via float4 (1024 tasks)
  const float* xb = x + (size_t)(b * 256 + t) * HWD + p0;
  for (int task = tid; task < 1024; task += 256) {
    int c = task >> 4, f4 = task & 15;
    *reinterpret_cast<float4*>(&xs[c][f4 * 4]) =
        *reinterpret_cast<const float4*>(&xb[c * 12544 + f4 * 4]);
  }
  __syncthreads();

  int oi = tid & 15, pi = tid >> 4;
  float acc[3][4][4];  // [g][oj][pj]
#pragma unroll
  for (int g = 0; g < 3; ++g)
#pragma unroll
    for (int i = 0; i < 4; ++i)
#pragma unroll
      for (int j = 0; j < 4; ++j) acc[g][i][j] = 0.f;

#pragma unroll 8
  for (int c = 0; c < 64; ++c) {
    float4 xv = *reinterpret_cast<const float4*>(&xs[c][pi * 4]);
#pragma unroll
    for (int g = 0; g < 3; ++g) {
      float4 wv = *reinterpret_cast<const float4*>(&ws[c][g * 64 + oi * 4]);
      acc[g][0][0] += wv.x * xv.x; acc[g][0][1] += wv.x * xv.y;
      acc[g][0][2] += wv.x * xv.z; acc[g][0][3] += wv.x * xv.w;
      acc[g][1][0] += wv.y * xv.x; acc[g][1][1] += wv.y * xv.y;
      acc[g][1][2] += wv.y * xv.z; acc[g][1][3] += wv.y * xv.w;
      acc[g][2][0] += wv.z * xv.x; acc[g][2][1] += wv.z * xv.y;
      acc[g][2][2] += wv.z * xv.z; acc[g][2][3] += wv.z * xv.w;
      acc[g][3][0] += wv.w * xv.x; acc[g][3][1] += wv.w * xv.y;
      acc[g][3][2] += wv.w * xv.z; acc[g][3][3] += wv.w * xv.w;
    }
  }

  // epilogue: bias, bf16 pack, store uint2 per (g,pos)
#pragma unroll
  for (int g = 0; g < 3; ++g) {
    float4 bv = *reinterpret_cast<const float4*>(&b_in[g * 64 + oi * 4]);
    u16* og = (g == 0 ? th : (g == 1 ? ph : gg));
#pragma unroll
    for (int pj = 0; pj < 4; ++pj) {
      int p = p0 + pi * 4 + pj;
      uint2 v;
      v.x = pack2(acc[g][0][pj] + bv.x, acc[g][1][pj] + bv.y);
      v.y = pack2(acc[g][2][pj] + bv.z, acc[g][3][pj] + bv.w);
      *reinterpret_cast<uint2*>(&og[((size_t)bt * HWD + p) * 64 + oi * 4]) = v;
    }
  }
}

// ---------------- K2: fused attention + fold + conv_out, per 4x4 spatial tile ----------------
__global__ __launch_bounds__(512) void k_attn(const u16* __restrict__ th, const u16* __restrict__ ph,
                                              const u16* __restrict__ gg,
                                              const float* __restrict__ w_out,
                                              const float* __restrict__ b_out,
                                              u16* __restrict__ pre) {
  __shared__ u16 ph_s[64][4][72];   // [Z(8x8 halo)][rho][c pad 64->72]
  __shared__ u16 g_s[64][4][72];
  __shared__ u16 th_s[16][4][72];   // [pos(4x4)][tau][c]
  __shared__ float a_s[16][25][4][4];   // [pos][d][rho][tau], includes cnt/36 scale
  __shared__ float folded_s[16][4][64]; // [pos][tau][c]
  __shared__ u16 w_s[64][66];           // w_out transposed [c][o], pad 66

  int bi = blockIdx.x;
  int b = bi / 196, tile = bi % 196;
  int ty = tile / 14, tx = tile % 14;
  int y0 = ty * 4, x0 = tx * 4;
  int tid = threadIdx.x;

  // stage phi & g halo (8x8 positions, zero-filled OOB)
  for (int task = tid; task < 2048; task += 512) {
    int rho = task >> 9, rem = task & 511, Z = rem >> 3, ch = rem & 7;
    int zy = Z >> 3, zx = Z & 7;
    int Y = y0 - 2 + zy, X = x0 - 2 + zx;
    uint4 vp = make_uint4(0, 0, 0, 0), vg = make_uint4(0, 0, 0, 0);
    if (Y >= 0 && Y < HH && X >= 0 && X < HH) {
      int gi = (((b * 4 + rho) * HWD) + Y * HH + X) * 64 + ch * 8;
      vp = *reinterpret_cast<const uint4*>(&ph[gi]);
      vg = *reinterpret_cast<const uint4*>(&gg[gi]);
    }
    *reinterpret_cast<uint4*>(&ph_s[Z][rho][ch * 8]) = vp;
    *reinterpret_cast<uint4*>(&g_s[Z][rho][ch * 8]) = vg;
  }
  // stage theta tile
  {
    int tau = tid >> 7, rem = tid & 127, pos = rem >> 3, ch = rem & 7;
    int Y = y0 + (pos >> 2), X = x0 + (pos & 3);
    int gi = (((b * 4 + tau) * HWD) + Y * HH + X) * 64 + ch * 8;
    *reinterpret_cast<uint4*>(&th_s[pos][tau][ch * 8]) = *reinterpret_cast<const uint4*>(&th[gi]);
  }
  // stage w_out transposed (bf16)
  for (int task = tid; task < 4096; task += 512) {
    int o = task >> 6, c = task & 63;
    w_s[c][o] = f2bf(w_out[task]);
  }
  __syncthreads();

  // Phase A: A'[pos][d][rho][tau] = (theta(Y,tau) . phi(Y+d,rho)) * cntx*cnty/36
  {
    int pos = tid >> 5, tau = (tid >> 3) & 3, rho = (tid >> 1) & 3, dh = tid & 1;
    int py = pos >> 2, px = pos & 3;
    float tr[64];
    const uint4* tp = reinterpret_cast<const uint4*>(&th_s[pos][tau][0]);
#pragma unroll
    for (int k = 0; k < 8; ++k) {
      uint4 v = tp[k];
      tr[k * 8 + 0] = bf_lo(v.x); tr[k * 8 + 1] = bf_hi(v.x);
      tr[k * 8 + 2] = bf_lo(v.y); tr[k * 8 + 3] = bf_hi(v.y);
      tr[k * 8 + 4] = bf_lo(v.z); tr[k * 8 + 5] = bf_hi(v.z);
      tr[k * 8 + 6] = bf_lo(v.w); tr[k * 8 + 7] = bf_hi(v.w);
    }
    for (int dd = dh; dd < 25; dd += 2) {
      int q = dd / 5;
      int dy = q - 2, dx = dd - q * 5 - 2;
      int Z = (py + 2 + dy) * 8 + (px + 2 + dx);
      const uint4* pp = reinterpret_cast<const uint4*>(&ph_s[Z][rho][0]);
      float a0 = 0.f, a1 = 0.f, a2 = 0.f, a3 = 0.f;
#pragma unroll
      for (int k = 0; k < 8; ++k) {
        uint4 v = pp[k];
        a0 += bf_lo(v.x) * tr[k * 8 + 0]; a1 += bf_hi(v.x) * tr[k * 8 + 1];
        a2 += bf_lo(v.y) * tr[k * 8 + 2]; a3 += bf_hi(v.y) * tr[k * 8 + 3];
        a0 += bf_lo(v.z) * tr[k * 8 + 4]; a1 += bf_hi(v.z) * tr[k * 8 + 5];
        a2 += bf_lo(v.w) * tr[k * 8 + 6]; a3 += bf_hi(v.w) * tr[k * 8 + 7];
      }
      float acc = (a0 + a1) + (a2 + a3);
      float sc = cntf(dy, y0 + py) * cntf(dx, x0 + px) * (1.f / 36.f);
      a_s[pos][dd][rho][tau] = acc * sc;
    }
  }
  __syncthreads();

  // Phase B: folded[pos][tau][c] = sum_{d,rho} A' * g[c,rho,Y+d]
  {
    int pos = tid >> 5, cg = tid & 31, c2 = cg * 2;
    int py = pos >> 2, px = pos & 3;
    float f0[4] = {0, 0, 0, 0}, f1[4] = {0, 0, 0, 0};
    for (int dd = 0; dd < 25; ++dd) {
      int q = dd / 5;
      int dy = q - 2, dx = dd - q * 5 - 2;
      int Z = (py + 2 + dy) * 8 + (px + 2 + dx);
#pragma unroll
      for (int r = 0; r < 4; ++r) {
        float4 a4 = *reinterpret_cast<const float4*>(&a_s[pos][dd][r][0]);
        u32 gv = *reinterpret_cast<const u32*>(&g_s[Z][r][c2]);
        float ga = bf_lo(gv), gb = bf_hi(gv);
        f0[0] += ga * a4.x; f0[1] += ga * a4.y; f0[2] += ga * a4.z; f0[3] += ga * a4.w;
        f1[0] += gb * a4.x; f1[1] += gb * a4.y; f1[2] += gb * a4.z; f1[3] += gb * a4.w;
      }
    }
#pragma unroll
    for (int t = 0; t < 4; ++t) {
      folded_s[pos][t][c2] = f0[t];
      folded_s[pos][t][c2 + 1] = f1[t];
    }
  }
  __syncthreads();

  // Phase C: preBN[o,tau] = w_out . folded + b_out ; store bf16 [b][tau][hw][o]
  {
    int pos = tid >> 5, og = tid & 31, o2 = og * 2;
    float a0[4] = {0, 0, 0, 0}, a1[4] = {0, 0, 0, 0};
    for (int c = 0; c < 64; ++c) {
      u32 wv = *reinterpret_cast<const u32*>(&w_s[c][o2]);
      float w0 = bf_lo(wv), w1 = bf_hi(wv);
#pragma unroll
      for (int t = 0; t < 4; ++t) {
        float fv = folded_s[pos][t][c];
        a0[t] += w0 * fv; a1[t] += w1 * fv;
      }
    }
    float bo0 = b_out[o2], bo1 = b_out[o2 + 1];
    int hw = (y0 + (pos >> 2)) * HH + x0 + (pos & 3);
#pragma unroll
    for (int t = 0; t < 4; ++t) {
      u32 pv = pack2(a0[t] + bo0, a1[t] + bo1);
      *reinterpret_cast<u32*>(&pre[(((b * 4 + t) * HWD) + hw) * 64 + o2]) = pv;
    }
  }
}

// ---------------- K3: per-channel sum / sumsq of preBN ----------------
__global__ __launch_bounds__(256) void k_stats(const u16* __restrict__ pre, float* __restrict__ stats) {
  __shared__ float rs[2][4][64];
  int tid = threadIdx.x;
  int o = tid & 63, pg = tid >> 6;
  int base = blockIdx.x * 1024;
  float s = 0.f, q = 0.f;
  for (int j = 0; j < 256; ++j) {
    int P = base + pg + j * 4;
    float v = bf16u(pre[P * 64 + o]);
    s += v; q += v * v;
  }
  rs[0][pg][o] = s; rs[1][pg][o] = q;
  __syncthreads();
  if (tid < 64) {
    float ts = rs[0][0][tid] + rs[0][1][tid] + rs[0][2][tid] + rs[0][3][tid];
    float tq = rs[1][0][tid] + rs[1][1][tid] + rs[1][2][tid] + rs[1][3][tid];
    atomicAdd(&stats[tid], ts);
    atomicAdd(&stats[64 + tid], tq);
  }
}

// ---------------- K4: BN finalize + residual ----------------
__global__ __launch_bounds__(256) void k_final(const float* __restrict__ x, const u16* __restrict__ pre,
                                               const float* __restrict__ stats,
                                               const float* __restrict__ gamma,
                                               const float* __restrict__ beta,
                                               float* __restrict__ out) {
  __shared__ u16 pre_s[64][66];  // pad 66 -> stride 33 words: 2-way free
  int bi = blockIdx.x;
  int bt = bi / 49, ck = bi % 49;
  int b = bt >> 2, t = bt & 3;
  int hw0 = ck * 64;
  int tid = threadIdx.x;
  const u32* src = reinterpret_cast<const u32*>(pre) + (bt * HWD + hw0) * 32;
  for (int task = tid; task < 2048; task += 256) {
    int p = task >> 5, cu = task & 31;
    *reinterpret_cast<u32*>(&pre_s[p][cu * 2]) = src[p * 32 + cu];
  }
  __syncthreads();
  int cg = tid >> 6, pl = tid & 63;
  int hw = hw0 + pl;
  const float invN = 1.f / NTOT;
  for (int i = 0; i < 16; ++i) {
    int c = cg * 16 + i;
    float mu = stats[c] * invN;
    float var = stats[64 + c] * invN - mu * mu;
    float scv = rsqrtf(var + 1e-5f) * gamma[c];
    float sh = beta[c] - mu * scv;
    float v = bf16u(pre_s[pl][c]);
    int oi = ((b * 64 + c) * 4 + t) * HWD + hw;
    out[oi] = x[oi] + v * scv + sh;
  }
}

extern "C" void kernel_launch(void* const* d_in, const int* in_sizes, int n_in,
                              void* d_out, int out_size, void* d_ws, size_t ws_size,
                              hipStream_t stream) {
  const float* x = (const float*)d_in[0];
  const float* w_in = (const float*)d_in[1];
  const float* b_in = (const float*)d_in[2];
  const float* w_out = (const float*)d_in[3];
  const float* b_out = (const float*)d_in[4];
  const float* gamma = (const float*)d_in[5];
  const float* beta = (const float*)d_in[6];
  float* out = (float*)d_out;

  const size_t NE = (size_t)BB * TT * HWD * 64;  // 6,422,528 elements per bf16 tensor
  u16* th = (u16*)d_ws;
  u16* ph = th + NE;
  u16* gg = ph + NE;
  u16* pre = gg + NE;
  float* stats = (float*)((char*)d_ws + 4 * NE * sizeof(u16));  // 128 floats

  k_conv_in<<<dim3(BB * TT * 49), dim3(256), 0, stream>>>(x, w_in, b_in, th, ph, gg, stats);
  k_attn<<<dim3(BB * 196), dim3(512), 0, stream>>>(th, ph, gg, w_out, b_out, pre);
  k_stats<<<dim3(98), dim3(256), 0, stream>>>(pre, stats);
  k_final<<<dim3(BB * TT * 49), dim3(256), 0, stream>>>(x, pre, stats, gamma, beta, out);
}

// Round 3
// 130.248 us; speedup vs baseline: 2.3540x; 1.5442x over previous
//
#include <hip/hip_runtime.h>

// LocalAttention collapsed form, MFMA edition.
// folded[c,t,Y] = (1/36) sum_{c'} theta[c',t,Y] * sum_d cnt(d,Y) sum_r phi[c',r,Y+d]*g[c,r,Y+d]
// k_attn per 4x4 tile: A = phi^T theta (MFMA), scale by cnt, folded = A*g (MFMA), pre = W*folded (MFMA).
// ws: theta/phi (pos-major), g (channel-major), preBN = 4 bf16 tensors + 128 f32 stats.

typedef unsigned short u16;
typedef unsigned int u32;
using f32x4 = __attribute__((ext_vector_type(4))) float;
using bf16x8 = __attribute__((ext_vector_type(8))) short;

#define BB 8
#define TT 4
#define HH 56
#define HWD 3136
#define NTOT 100352.0f

__device__ __forceinline__ float bf_lo(u32 u) { return __uint_as_float(u << 16); }
__device__ __forceinline__ float bf_hi(u32 u) { return __uint_as_float(u & 0xffff0000u); }
__device__ __forceinline__ float bf16u(u16 u) { return __uint_as_float(((u32)u) << 16); }
__device__ __forceinline__ u16 f2bf(float f) {
  u32 u = __float_as_uint(f);
  u32 r = (u + 0x7fffu + ((u >> 16) & 1u)) >> 16;
  return (u16)r;
}
__device__ __forceinline__ u32 pack2(float a, float b) {
  return (u32)f2bf(a) | ((u32)f2bf(b) << 16);
}
__device__ __forceinline__ int imax(int a, int b) { return a > b ? a : b; }
__device__ __forceinline__ int imin(int a, int b) { return a < b ? a : b; }
__device__ __forceinline__ float cntf(int d, int p) {
  int lo = imax(-1, imax(-1 - d, p - (HH - 1)));
  int hi = imin(1, imin(1 - d, p));
  int n = hi - lo + 1;
  return n > 0 ? (float)n : 0.f;
}

// ---------------- K1: conv_in as register-tiled GEMM ----------------
// outputs: th, ph pos-major [b][t][hw][c]; g channel-major [b][c][t][hw]
__global__ __launch_bounds__(256) void k_conv_in(const float* __restrict__ x,
                                                 const float* __restrict__ w_in,
                                                 const float* __restrict__ b_in,
                                                 u16* __restrict__ th, u16* __restrict__ ph,
                                                 u16* __restrict__ g2, float* __restrict__ stats) {
  __shared__ float ws[64][195];
  __shared__ float xs[64][64];
  if (blockIdx.x == 0 && threadIdx.x < 128) stats[threadIdx.x] = 0.f;
  int bt = blockIdx.x / 49, chunk = blockIdx.x % 49;
  int b = bt >> 2, t = bt & 3;
  int p0 = chunk * 64;
  int tid = threadIdx.x;

  for (int task = tid; task < 12288; task += 256) {
    int o = task >> 6, c = task & 63;
    ws[c][o] = w_in[task];
  }
  const float* xb = x + (size_t)(b * 256 + t) * HWD + p0;
  for (int task = tid; task < 1024; task += 256) {
    int c = task >> 4, f4 = task & 15;
    *reinterpret_cast<float4*>(&xs[c][f4 * 4]) =
        *reinterpret_cast<const float4*>(&xb[c * 12544 + f4 * 4]);
  }
  __syncthreads();

  int oi = tid & 15, pi = tid >> 4;
  float acc[3][4][4];
#pragma unroll
  for (int g = 0; g < 3; ++g)
#pragma unroll
    for (int i = 0; i < 4; ++i)
#pragma unroll
      for (int j = 0; j < 4; ++j) acc[g][i][j] = 0.f;

#pragma unroll 8
  for (int c = 0; c < 64; ++c) {
    float4 xv = *reinterpret_cast<const float4*>(&xs[c][pi * 4]);
#pragma unroll
    for (int g = 0; g < 3; ++g) {
      float4 wv = *reinterpret_cast<const float4*>(&ws[c][g * 64 + oi * 4]);
      acc[g][0][0] += wv.x * xv.x; acc[g][0][1] += wv.x * xv.y;
      acc[g][0][2] += wv.x * xv.z; acc[g][0][3] += wv.x * xv.w;
      acc[g][1][0] += wv.y * xv.x; acc[g][1][1] += wv.y * xv.y;
      acc[g][1][2] += wv.y * xv.z; acc[g][1][3] += wv.y * xv.w;
      acc[g][2][0] += wv.z * xv.x; acc[g][2][1] += wv.z * xv.y;
      acc[g][2][2] += wv.z * xv.z; acc[g][2][3] += wv.z * xv.w;
      acc[g][3][0] += wv.w * xv.x; acc[g][3][1] += wv.w * xv.y;
      acc[g][3][2] += wv.w * xv.z; acc[g][3][3] += wv.w * xv.w;
    }
  }

#pragma unroll
  for (int g = 0; g < 2; ++g) {
    float4 bv = *reinterpret_cast<const float4*>(&b_in[g * 64 + oi * 4]);
    u16* og = (g == 0 ? th : ph);
#pragma unroll
    for (int pj = 0; pj < 4; ++pj) {
      int p = p0 + pi * 4 + pj;
      uint2 v;
      v.x = pack2(acc[g][0][pj] + bv.x, acc[g][1][pj] + bv.y);
      v.y = pack2(acc[g][2][pj] + bv.z, acc[g][3][pj] + bv.w);
      *reinterpret_cast<uint2*>(&og[((size_t)bt * HWD + p) * 64 + oi * 4]) = v;
    }
  }
  // g tensor: channel-major [b][o][t][hw]
  {
    float4 bv = *reinterpret_cast<const float4*>(&b_in[128 + oi * 4]);
    float bvc[4] = {bv.x, bv.y, bv.z, bv.w};
#pragma unroll
    for (int i = 0; i < 4; ++i) {
      uint2 v;
      v.x = pack2(acc[2][i][0] + bvc[i], acc[2][i][1] + bvc[i]);
      v.y = pack2(acc[2][i][2] + bvc[i], acc[2][i][3] + bvc[i]);
      *reinterpret_cast<uint2*>(&g2[(((size_t)b * 64 + oi * 4 + i) * 4 + t) * HWD + p0 + pi * 4]) = v;
    }
  }
}

// ---------------- K2: MFMA attention ----------------
// LDS map (bytes): ph[256 rows x 128] @0 (aliased later by As[64 rows x 512])
//                  g [64 rows x 512] @32768 (aliased later by w_s[64 x 128])
//                  th[64 rows x 128] @65536 (aliased later by folded[64 x 128])
//                  tables @73728 (cyt 32 f32, cxt 32 f32)
#define PH_OFF 0
#define AS_OFF 0
#define G_OFF 32768
#define W_OFF 32768
#define TH_OFF 65536
#define FOLD_OFF 65536
#define TAB_OFF 73728

__global__ __launch_bounds__(512, 4) void k_attn(const u16* __restrict__ th, const u16* __restrict__ ph,
                                                 const u16* __restrict__ g2,
                                                 const float* __restrict__ w_out,
                                                 const float* __restrict__ b_out,
                                                 u16* __restrict__ pre) {
  __shared__ __align__(16) char sm[73984];

  int bi = blockIdx.x;
  int b = bi / 196, tile = bi % 196;
  int ty = tile / 14, tx = tile % 14;
  int y0 = ty * 4, x0 = tx * 4;
  int tid = threadIdx.x;
  int w = tid >> 6, lane = tid & 63;
  int lr = lane & 15, lk = lane >> 4;

  // ---- stage phi: rows (rho,Z) = rho*64+Z, cols c, swizzled ----
  for (int task = tid; task < 2048; task += 512) {
    int row = task >> 3, ch = task & 7;
    int rho = row >> 6, Z = row & 63, zy = Z >> 3, zx = Z & 7;
    int Y = y0 - 2 + zy, X = x0 - 2 + zx;
    uint4 v = make_uint4(0, 0, 0, 0);
    if ((unsigned)Y < HH && (unsigned)X < HH)
      v = *reinterpret_cast<const uint4*>(&ph[(((size_t)b * 4 + rho) * HWD + Y * HH + X) * 64 + ch * 8]);
    *reinterpret_cast<uint4*>(sm + PH_OFF + row * 128 + ((ch * 16) ^ ((row & 7) << 4))) = v;
  }
  // ---- stage theta: rows (pos,tau) = pos*4+tau ----
  {
    int row = tid >> 3, ch = tid & 7;
    int pos = row >> 2, tau = row & 3;
    int Y = y0 + (pos >> 2), X = x0 + (pos & 3);
    uint4 v = *reinterpret_cast<const uint4*>(&th[(((size_t)b * 4 + tau) * HWD + Y * HH + X) * 64 + ch * 8]);
    *reinterpret_cast<uint4*>(sm + TH_OFF + row * 128 + ((ch * 16) ^ ((row & 7) << 4))) = v;
  }
  // ---- stage g channel-major: rows c, cols (rho,zy,zx) ----
  for (int task = tid; task < 2048; task += 512) {
    int c = task >> 5, rho = (task >> 3) & 3, zy = task & 7;
    int Y = y0 - 2 + zy;
    u32 pv[4] = {0, 0, 0, 0};
    if ((unsigned)Y < HH) {
      size_t rowbase = (((size_t)b * 64 + c) * 4 + rho) * HWD + (size_t)Y * HH;
      int xb = x0 - 2;
#pragma unroll
      for (int j = 0; j < 4; ++j) {
        int X = xb + 2 * j;
        if ((unsigned)X < HH) pv[j] = *reinterpret_cast<const u32*>(&g2[rowbase + X]);
      }
    }
    uint4 v = make_uint4(pv[0], pv[1], pv[2], pv[3]);
    *reinterpret_cast<uint4*>(sm + G_OFF + c * 512 + ((16 * (rho * 8 + zy)) ^ ((c & 7) << 4))) = v;
  }
  // ---- cnt tables (scale 1/36 folded into cyt) ----
  if (tid < 32) {
    int zy = tid >> 2, py = tid & 3;
    reinterpret_cast<float*>(sm + TAB_OFF)[tid] = cntf(zy - 2 - py, y0 + py) * (1.f / 36.f);
  } else if (tid < 64) {
    int i = tid - 32;
    int zx = i >> 2, px = i & 3;
    reinterpret_cast<float*>(sm + TAB_OFF + 128)[i] = cntf(zx - 2 - px, x0 + px);
  }
  __syncthreads();

  // ---- Phase A: D[(rho,Z)][(pos,tau)] = sum_c phi*theta; 64 tiles, 8/wave ----
  bf16x8 tb[4][2];
#pragma unroll
  for (int nt = 0; nt < 4; ++nt)
#pragma unroll
    for (int kt = 0; kt < 2; ++kt) {
      int row = nt * 16 + lr;
      tb[nt][kt] = *reinterpret_cast<const bf16x8*>(sm + TH_OFF + row * 128 + ((kt * 64 + lk * 16) ^ ((row & 7) << 4)));
    }
  f32x4 accA[2][4];
#pragma unroll
  for (int mi = 0; mi < 2; ++mi)
#pragma unroll
    for (int nt = 0; nt < 4; ++nt) accA[mi][nt] = (f32x4){0.f, 0.f, 0.f, 0.f};
#pragma unroll
  for (int mi = 0; mi < 2; ++mi) {
    int mrow = (w * 2 + mi) * 16 + lr;
#pragma unroll
    for (int kt = 0; kt < 2; ++kt) {
      bf16x8 af = *reinterpret_cast<const bf16x8*>(sm + PH_OFF + mrow * 128 + ((kt * 64 + lk * 16) ^ ((mrow & 7) << 4)));
#pragma unroll
      for (int nt = 0; nt < 4; ++nt)
        accA[mi][nt] = __builtin_amdgcn_mfma_f32_16x16x32_bf16(af, tb[nt][kt], accA[mi][nt], 0, 0, 0);
    }
  }
  __syncthreads();  // phi reads done; As may overwrite

  // ---- Phase A epilogue: scale by cnt, pack bf16, write As[(pos,tau)][(rho,Z)] ----
  {
    const float* cyt = reinterpret_cast<const float*>(sm + TAB_OFF);
    const float* cxt = reinterpret_cast<const float*>(sm + TAB_OFF + 128);
#pragma unroll
    for (int mi = 0; mi < 2; ++mi) {
      int mbase = (w * 2 + mi) * 16 + lk * 4;
#pragma unroll
      for (int nt = 0; nt < 4; ++nt) {
        int n = nt * 16 + lr;
        int pos = n >> 2;
        int py = pos >> 2, px = pos & 3;
        float sc[4];
#pragma unroll
        for (int r = 0; r < 4; ++r) {
          int Z = (mbase + r) & 63;
          sc[r] = cyt[(Z >> 3) * 4 + py] * cxt[(Z & 7) * 4 + px];
        }
        f32x4 a = accA[mi][nt];
        uint2 vv;
        vv.x = pack2(a.x * sc[0], a.y * sc[1]);
        vv.y = pack2(a.z * sc[2], a.w * sc[3]);
        *reinterpret_cast<uint2*>(sm + AS_OFF + n * 512 + ((mbase * 2) ^ ((n & 7) << 4))) = vv;
      }
    }
  }
  __syncthreads();

  // ---- Phase B: folded[(pos,tau)][c] = sum_{rho,Z} As * g; 16 tiles, 2/wave ----
  int mtB = w & 3, ntb = (w >> 2) * 2;
  f32x4 accB[2];
  accB[0] = (f32x4){0.f, 0.f, 0.f, 0.f};
  accB[1] = (f32x4){0.f, 0.f, 0.f, 0.f};
  {
    int arow = mtB * 16 + lr;
#pragma unroll
    for (int kt = 0; kt < 8; ++kt) {
      bf16x8 af = *reinterpret_cast<const bf16x8*>(sm + AS_OFF + arow * 512 + ((kt * 64 + lk * 16) ^ ((arow & 7) << 4)));
#pragma unroll
      for (int j = 0; j < 2; ++j) {
        int brow = (ntb + j) * 16 + lr;
        bf16x8 bf = *reinterpret_cast<const bf16x8*>(sm + G_OFF + brow * 512 + ((kt * 64 + lk * 16) ^ ((brow & 7) << 4)));
        accB[j] = __builtin_amdgcn_mfma_f32_16x16x32_bf16(af, bf, accB[j], 0, 0, 0);
      }
    }
  }
  __syncthreads();  // g reads done; w_s may overwrite

  // ---- write folded (bf16) + stage w_out ----
#pragma unroll
  for (int j = 0; j < 2; ++j) {
    int n = (ntb + j) * 16 + lr;  // c
#pragma unroll
    for (int r = 0; r < 4; ++r) {
      int m = mtB * 16 + lk * 4 + r;  // (pos,tau)
      *reinterpret_cast<u16*>(sm + FOLD_OFF + m * 128 + ((n * 2) ^ ((m & 7) << 4))) = f2bf(accB[j][r]);
    }
  }
  {
    int o = tid >> 3, cg = tid & 7;
    float4 w0 = *reinterpret_cast<const float4*>(&w_out[o * 64 + cg * 8]);
    float4 w1 = *reinterpret_cast<const float4*>(&w_out[o * 64 + cg * 8 + 4]);
    uint4 wv = make_uint4(pack2(w0.x, w0.y), pack2(w0.z, w0.w), pack2(w1.x, w1.y), pack2(w1.z, w1.w));
    *reinterpret_cast<uint4*>(sm + W_OFF + o * 128 + ((cg * 16) ^ ((o & 7) << 4))) = wv;
  }
  __syncthreads();

  // ---- Phase C: pre[o][(pos,tau)] = W . folded^T; 16 tiles, 2/wave ----
  int mtC = w & 3, ntc = (w >> 2) * 2;
  f32x4 accC[2];
  accC[0] = (f32x4){0.f, 0.f, 0.f, 0.f};
  accC[1] = (f32x4){0.f, 0.f, 0.f, 0.f};
  {
    int arow = mtC * 16 + lr;
#pragma unroll
    for (int kt = 0; kt < 2; ++kt) {
      bf16x8 af = *reinterpret_cast<const bf16x8*>(sm + W_OFF + arow * 128 + ((kt * 64 + lk * 16) ^ ((arow & 7) << 4)));
#pragma unroll
      for (int j = 0; j < 2; ++j) {
        int brow = (ntc + j) * 16 + lr;
        bf16x8 bf = *reinterpret_cast<const bf16x8*>(sm + FOLD_OFF + brow * 128 + ((kt * 64 + lk * 16) ^ ((brow & 7) << 4)));
        accC[j] = __builtin_amdgcn_mfma_f32_16x16x32_bf16(af, bf, accC[j], 0, 0, 0);
      }
    }
  }
  {
    int o = mtC * 16 + lk * 4;
    float4 bo = *reinterpret_cast<const float4*>(&b_out[o]);
#pragma unroll
    for (int j = 0; j < 2; ++j) {
      int n = (ntc + j) * 16 + lr;
      int pos = n >> 2, tau = n & 3;
      int hw = (y0 + (pos >> 2)) * HH + x0 + (pos & 3);
      uint2 v;
      v.x = pack2(accC[j].x + bo.x, accC[j].y + bo.y);
      v.y = pack2(accC[j].z + bo.z, accC[j].w + bo.w);
      *reinterpret_cast<uint2*>(&pre[(((size_t)b * 4 + tau) * HWD + hw) * 64 + o]) = v;
    }
  }
}

// ---------------- K3: per-channel sum / sumsq of preBN ----------------
__global__ __launch_bounds__(256) void k_stats(const u16* __restrict__ pre, float* __restrict__ stats) {
  __shared__ float rs[2][4][64];
  int tid = threadIdx.x;
  int o = tid & 63, pg = tid >> 6;
  int base = blockIdx.x * 1024;
  float s = 0.f, q = 0.f;
  for (int j = 0; j < 256; ++j) {
    int P = base + pg + j * 4;
    float v = bf16u(pre[(size_t)P * 64 + o]);
    s += v; q += v * v;
  }
  rs[0][pg][o] = s; rs[1][pg][o] = q;
  __syncthreads();
  if (tid < 64) {
    float ts = rs[0][0][tid] + rs[0][1][tid] + rs[0][2][tid] + rs[0][3][tid];
    float tq = rs[1][0][tid] + rs[1][1][tid] + rs[1][2][tid] + rs[1][3][tid];
    atomicAdd(&stats[tid], ts);
    atomicAdd(&stats[64 + tid], tq);
  }
}

// ---------------- K4: BN finalize + residual ----------------
__global__ __launch_bounds__(256) void k_final(const float* __restrict__ x, const u16* __restrict__ pre,
                                               const float* __restrict__ stats,
                                               const float* __restrict__ gamma,
                                               const float* __restrict__ beta,
                                               float* __restrict__ out) {
  __shared__ u16 pre_s[64][66];
  int bi = blockIdx.x;
  int bt = bi / 49, ck = bi % 49;
  int b = bt >> 2, t = bt & 3;
  int hw0 = ck * 64;
  int tid = threadIdx.x;
  const u32* src = reinterpret_cast<const u32*>(pre) + ((size_t)bt * HWD + hw0) * 32;
  for (int task = tid; task < 2048; task += 256) {
    int p = task >> 5, cu = task & 31;
    *reinterpret_cast<u32*>(&pre_s[p][cu * 2]) = src[p * 32 + cu];
  }
  __syncthreads();
  int cg = tid >> 6, pl = tid & 63;
  int hw = hw0 + pl;
  const float invN = 1.f / NTOT;
  for (int i = 0; i < 16; ++i) {
    int c = cg * 16 + i;
    float mu = stats[c] * invN;
    float var = stats[64 + c] * invN - mu * mu;
    float scv = rsqrtf(var + 1e-5f) * gamma[c];
    float sh = beta[c] - mu * scv;
    float v = bf16u(pre_s[pl][c]);
    size_t oi = ((size_t)(b * 64 + c) * 4 + t) * HWD + hw;
    out[oi] = x[oi] + v * scv + sh;
  }
}

extern "C" void kernel_launch(void* const* d_in, const int* in_sizes, int n_in,
                              void* d_out, int out_size, void* d_ws, size_t ws_size,
                              hipStream_t stream) {
  const float* x = (const float*)d_in[0];
  const float* w_in = (const float*)d_in[1];
  const float* b_in = (const float*)d_in[2];
  const float* w_out = (const float*)d_in[3];
  const float* b_out = (const float*)d_in[4];
  const float* gamma = (const float*)d_in[5];
  const float* beta = (const float*)d_in[6];
  float* out = (float*)d_out;

  const size_t NE = (size_t)BB * TT * HWD * 64;
  u16* th = (u16*)d_ws;
  u16* ph = th + NE;
  u16* g2 = ph + NE;
  u16* pre = g2 + NE;
  float* stats = (float*)((char*)d_ws + 4 * NE * sizeof(u16));

  k_conv_in<<<dim3(BB * TT * 49), dim3(256), 0, stream>>>(x, w_in, b_in, th, ph, g2, stats);
  k_attn<<<dim3(BB * 196), dim3(512), 0, stream>>>(th, ph, g2, w_out, b_out, pre);
  k_stats<<<dim3(98), dim3(256), 0, stream>>>(pre, stats);
  k_final<<<dim3(BB * TT * 49), dim3(256), 0, stream>>>(x, pre, stats, gamma, beta, out);
}

// Round 4
// 93.500 us; speedup vs baseline: 3.2791x; 1.3930x over previous
//
#include <hip/hip_runtime.h>

// LocalAttention collapsed form, all-MFMA edition.
// folded[c,t,Y] = (1/36) sum_{c'} theta[c',t,Y] * sum_d cnt(d,Y) sum_r phi[c',r,Y+d]*g[c,r,Y+d]
// K1: conv_in as bf16 MFMA GEMM (W[192x64] x X[64x64]-tile, X transposed into LDS w/ 2-sided swizzle)
// K2: A = phi^T theta (MFMA), scale by cnt, folded = A*g (MFMA), pre = W*folded (MFMA).
// ws: theta/phi (pos-major), g (channel-major), preBN = 4 bf16 tensors + 128 f32 stats.

typedef unsigned short u16;
typedef unsigned int u32;
using f32x4 = __attribute__((ext_vector_type(4))) float;
using bf16x8 = __attribute__((ext_vector_type(8))) short;

#define BB 8
#define TT 4
#define HH 56
#define HWD 3136
#define NTOT 100352.0f

__device__ __forceinline__ float bf_lo(u32 u) { return __uint_as_float(u << 16); }
__device__ __forceinline__ float bf_hi(u32 u) { return __uint_as_float(u & 0xffff0000u); }
__device__ __forceinline__ float bf16u(u16 u) { return __uint_as_float(((u32)u) << 16); }
__device__ __forceinline__ u16 f2bf(float f) {
  u32 u = __float_as_uint(f);
  u32 r = (u + 0x7fffu + ((u >> 16) & 1u)) >> 16;
  return (u16)r;
}
__device__ __forceinline__ u32 pack2(float a, float b) {
  return (u32)f2bf(a) | ((u32)f2bf(b) << 16);
}
__device__ __forceinline__ int imax(int a, int b) { return a > b ? a : b; }
__device__ __forceinline__ int imin(int a, int b) { return a < b ? a : b; }
__device__ __forceinline__ float cntf(int d, int p) {
  int lo = imax(-1, imax(-1 - d, p - (HH - 1)));
  int hi = imin(1, imin(1 - d, p));
  int n = hi - lo + 1;
  return n > 0 ? (float)n : 0.f;
}

// ---------------- K1: conv_in as bf16 MFMA GEMM ----------------
// Per block: 64-position tile of one (b,t). W_lds [192 o][64 c] bf16; X_lds [64 p][64 c] bf16 (transposed).
// Outputs: th/ph pos-major [bt][hw][c]; g2 channel-major [b][c][t][hw].
#define K1_XOFF 24576
__global__ __launch_bounds__(256, 4) void k_conv_in(const float* __restrict__ x,
                                                    const float* __restrict__ w_in,
                                                    const float* __restrict__ b_in,
                                                    u16* __restrict__ th, u16* __restrict__ ph,
                                                    u16* __restrict__ g2, float* __restrict__ stats) {
  __shared__ __align__(16) char sm[24576 + 8192];
  if (blockIdx.x == 0 && threadIdx.x < 128) stats[threadIdx.x] = 0.f;
  int bt = blockIdx.x / 49, chunk = blockIdx.x % 49;
  int b = bt >> 2, t = bt & 3;
  int p0 = chunk * 64;
  int tid = threadIdx.x;

  // stage W: rows o, cols c, swizzle ((o&7)<<4). Coalesced float4 reads.
#pragma unroll
  for (int it = 0; it < 12; ++it) {
    int task = it * 256 + tid;
    int o = task >> 4, c4 = (task & 15) * 4;
    float4 wv = *reinterpret_cast<const float4*>(&w_in[o * 64 + c4]);
    uint2 pv;
    pv.x = pack2(wv.x, wv.y);
    pv.y = pack2(wv.z, wv.w);
    *reinterpret_cast<uint2*>(sm + o * 128 + ((c4 * 2) ^ ((o & 7) << 4))) = pv;
  }
  // stage X transposed: rows p, cols c. slot(p) = (p&7)^((p>>2)&7) spreads banks for
  // both the p4-varying writes and the (p&15)-varying reads (each <=2-way).
  const float* xb = x + ((size_t)b * 256 + t) * HWD + p0;  // + c*4*HWD
#pragma unroll
  for (int it = 0; it < 2; ++it) {
    int task = it * 256 + tid;
    int cp = task >> 4, p4 = task & 15;
    int c0 = cp * 2;
    float4 fa = *reinterpret_cast<const float4*>(&xb[(size_t)c0 * 4 * HWD + p4 * 4]);
    float4 fb = *reinterpret_cast<const float4*>(&xb[(size_t)(c0 + 1) * 4 * HWD + p4 * 4]);
    float va[4] = {fa.x, fa.y, fa.z, fa.w}, vb[4] = {fb.x, fb.y, fb.z, fb.w};
#pragma unroll
    for (int j = 0; j < 4; ++j) {
      int p = p4 * 4 + j;
      int slot = (p & 7) ^ ((p >> 2) & 7);
      *reinterpret_cast<u32*>(sm + K1_XOFF + p * 128 + ((c0 * 2) ^ (slot << 4))) = pack2(va[j], vb[j]);
    }
  }
  __syncthreads();

  int w = tid >> 6, lane = tid & 63, lr = lane & 15, lk = lane >> 4;
  f32x4 acc[3][4];
#pragma unroll
  for (int i = 0; i < 3; ++i)
#pragma unroll
    for (int n = 0; n < 4; ++n) acc[i][n] = (f32x4){0.f, 0.f, 0.f, 0.f};

#pragma unroll
  for (int kt = 0; kt < 2; ++kt) {
    bf16x8 af[3], bfr[4];
#pragma unroll
    for (int i = 0; i < 3; ++i) {
      int arow = (w * 3 + i) * 16 + lr;
      af[i] = *reinterpret_cast<const bf16x8*>(sm + arow * 128 + ((kt * 64 + lk * 16) ^ ((arow & 7) << 4)));
    }
#pragma unroll
    for (int n = 0; n < 4; ++n) {
      int brow = n * 16 + lr;
      int slot = (brow & 7) ^ ((brow >> 2) & 7);
      bfr[n] = *reinterpret_cast<const bf16x8*>(sm + K1_XOFF + brow * 128 + ((kt * 64 + lk * 16) ^ (slot << 4)));
    }
#pragma unroll
    for (int i = 0; i < 3; ++i)
#pragma unroll
      for (int n = 0; n < 4; ++n)
        acc[i][n] = __builtin_amdgcn_mfma_f32_16x16x32_bf16(af[i], bfr[n], acc[i][n], 0, 0, 0);
  }

  // epilogue: D col = p (lane&15), rows = o (lk*4 + r). gsel uniform per (w,i).
#pragma unroll
  for (int i = 0; i < 3; ++i) {
    int mt = w * 3 + i;
    int ob = mt * 16 + lk * 4;
    int gsel = ob >> 6, o = ob & 63;
    float4 bv = *reinterpret_cast<const float4*>(&b_in[ob]);
#pragma unroll
    for (int n = 0; n < 4; ++n) {
      int p = p0 + n * 16 + lr;
      f32x4 a = acc[i][n];
      if (gsel < 2) {
        u16* og = gsel == 0 ? th : ph;
        uint2 v;
        v.x = pack2(a.x + bv.x, a.y + bv.y);
        v.y = pack2(a.z + bv.z, a.w + bv.w);
        *reinterpret_cast<uint2*>(&og[((size_t)bt * HWD + p) * 64 + o]) = v;
      } else {
        float aa[4] = {a.x, a.y, a.z, a.w};
        float bb[4] = {bv.x, bv.y, bv.z, bv.w};
#pragma unroll
        for (int r = 0; r < 4; ++r)
          g2[(((size_t)b * 64 + o + r) * 4 + t) * HWD + p] = f2bf(aa[r] + bb[r]);
      }
    }
  }
}

// ---------------- K2: MFMA attention ----------------
#define PH_OFF 0
#define AS_OFF 0
#define G_OFF 32768
#define W_OFF 32768
#define TH_OFF 65536
#define FOLD_OFF 65536
#define TAB_OFF 73728

__global__ __launch_bounds__(512, 4) void k_attn(const u16* __restrict__ th, const u16* __restrict__ ph,
                                                 const u16* __restrict__ g2,
                                                 const float* __restrict__ w_out,
                                                 const float* __restrict__ b_out,
                                                 u16* __restrict__ pre) {
  __shared__ __align__(16) char sm[73984];

  int bi = blockIdx.x;
  int b = bi / 196, tile = bi % 196;
  int ty = tile / 14, tx = tile % 14;
  int y0 = ty * 4, x0 = tx * 4;
  int tid = threadIdx.x;
  int w = tid >> 6, lane = tid & 63;
  int lr = lane & 15, lk = lane >> 4;

  for (int task = tid; task < 2048; task += 512) {
    int row = task >> 3, ch = task & 7;
    int rho = row >> 6, Z = row & 63, zy = Z >> 3, zx = Z & 7;
    int Y = y0 - 2 + zy, X = x0 - 2 + zx;
    uint4 v = make_uint4(0, 0, 0, 0);
    if ((unsigned)Y < HH && (unsigned)X < HH)
      v = *reinterpret_cast<const uint4*>(&ph[(((size_t)b * 4 + rho) * HWD + Y * HH + X) * 64 + ch * 8]);
    *reinterpret_cast<uint4*>(sm + PH_OFF + row * 128 + ((ch * 16) ^ ((row & 7) << 4))) = v;
  }
  {
    int row = tid >> 3, ch = tid & 7;
    int pos = row >> 2, tau = row & 3;
    int Y = y0 + (pos >> 2), X = x0 + (pos & 3);
    uint4 v = *reinterpret_cast<const uint4*>(&th[(((size_t)b * 4 + tau) * HWD + Y * HH + X) * 64 + ch * 8]);
    *reinterpret_cast<uint4*>(sm + TH_OFF + row * 128 + ((ch * 16) ^ ((row & 7) << 4))) = v;
  }
  for (int task = tid; task < 2048; task += 512) {
    int c = task >> 5, rho = (task >> 3) & 3, zy = task & 7;
    int Y = y0 - 2 + zy;
    u32 pv[4] = {0, 0, 0, 0};
    if ((unsigned)Y < HH) {
      size_t rowbase = (((size_t)b * 64 + c) * 4 + rho) * HWD + (size_t)Y * HH;
      int xb = x0 - 2;
#pragma unroll
      for (int j = 0; j < 4; ++j) {
        int X = xb + 2 * j;
        if ((unsigned)X < HH) pv[j] = *reinterpret_cast<const u32*>(&g2[rowbase + X]);
      }
    }
    uint4 v = make_uint4(pv[0], pv[1], pv[2], pv[3]);
    *reinterpret_cast<uint4*>(sm + G_OFF + c * 512 + ((16 * (rho * 8 + zy)) ^ ((c & 7) << 4))) = v;
  }
  if (tid < 32) {
    int zy = tid >> 2, py = tid & 3;
    reinterpret_cast<float*>(sm + TAB_OFF)[tid] = cntf(zy - 2 - py, y0 + py) * (1.f / 36.f);
  } else if (tid < 64) {
    int i = tid - 32;
    int zx = i >> 2, px = i & 3;
    reinterpret_cast<float*>(sm + TAB_OFF + 128)[i] = cntf(zx - 2 - px, x0 + px);
  }
  __syncthreads();

  bf16x8 tb[4][2];
#pragma unroll
  for (int nt = 0; nt < 4; ++nt)
#pragma unroll
    for (int kt = 0; kt < 2; ++kt) {
      int row = nt * 16 + lr;
      tb[nt][kt] = *reinterpret_cast<const bf16x8*>(sm + TH_OFF + row * 128 + ((kt * 64 + lk * 16) ^ ((row & 7) << 4)));
    }
  f32x4 accA[2][4];
#pragma unroll
  for (int mi = 0; mi < 2; ++mi)
#pragma unroll
    for (int nt = 0; nt < 4; ++nt) accA[mi][nt] = (f32x4){0.f, 0.f, 0.f, 0.f};
#pragma unroll
  for (int mi = 0; mi < 2; ++mi) {
    int mrow = (w * 2 + mi) * 16 + lr;
#pragma unroll
    for (int kt = 0; kt < 2; ++kt) {
      bf16x8 af = *reinterpret_cast<const bf16x8*>(sm + PH_OFF + mrow * 128 + ((kt * 64 + lk * 16) ^ ((mrow & 7) << 4)));
#pragma unroll
      for (int nt = 0; nt < 4; ++nt)
        accA[mi][nt] = __builtin_amdgcn_mfma_f32_16x16x32_bf16(af, tb[nt][kt], accA[mi][nt], 0, 0, 0);
    }
  }
  __syncthreads();

  {
    const float* cyt = reinterpret_cast<const float*>(sm + TAB_OFF);
    const float* cxt = reinterpret_cast<const float*>(sm + TAB_OFF + 128);
#pragma unroll
    for (int mi = 0; mi < 2; ++mi) {
      int mbase = (w * 2 + mi) * 16 + lk * 4;
#pragma unroll
      for (int nt = 0; nt < 4; ++nt) {
        int n = nt * 16 + lr;
        int pos = n >> 2;
        int py = pos >> 2, px = pos & 3;
        float sc[4];
#pragma unroll
        for (int r = 0; r < 4; ++r) {
          int Z = (mbase + r) & 63;
          sc[r] = cyt[(Z >> 3) * 4 + py] * cxt[(Z & 7) * 4 + px];
        }
        f32x4 a = accA[mi][nt];
        uint2 vv;
        vv.x = pack2(a.x * sc[0], a.y * sc[1]);
        vv.y = pack2(a.z * sc[2], a.w * sc[3]);
        *reinterpret_cast<uint2*>(sm + AS_OFF + n * 512 + ((mbase * 2) ^ ((n & 7) << 4))) = vv;
      }
    }
  }
  __syncthreads();

  int mtB = w & 3, ntb = (w >> 2) * 2;
  f32x4 accB[2];
  accB[0] = (f32x4){0.f, 0.f, 0.f, 0.f};
  accB[1] = (f32x4){0.f, 0.f, 0.f, 0.f};
  {
    int arow = mtB * 16 + lr;
#pragma unroll
    for (int kt = 0; kt < 8; ++kt) {
      bf16x8 af = *reinterpret_cast<const bf16x8*>(sm + AS_OFF + arow * 512 + ((kt * 64 + lk * 16) ^ ((arow & 7) << 4)));
#pragma unroll
      for (int j = 0; j < 2; ++j) {
        int brow = (ntb + j) * 16 + lr;
        bf16x8 bfv = *reinterpret_cast<const bf16x8*>(sm + G_OFF + brow * 512 + ((kt * 64 + lk * 16) ^ ((brow & 7) << 4)));
        accB[j] = __builtin_amdgcn_mfma_f32_16x16x32_bf16(af, bfv, accB[j], 0, 0, 0);
      }
    }
  }
  __syncthreads();

#pragma unroll
  for (int j = 0; j < 2; ++j) {
    int n = (ntb + j) * 16 + lr;
#pragma unroll
    for (int r = 0; r < 4; ++r) {
      int m = mtB * 16 + lk * 4 + r;
      *reinterpret_cast<u16*>(sm + FOLD_OFF + m * 128 + ((n * 2) ^ ((m & 7) << 4))) = f2bf(accB[j][r]);
    }
  }
  {
    int o = tid >> 3, cg = tid & 7;
    float4 w0 = *reinterpret_cast<const float4*>(&w_out[o * 64 + cg * 8]);
    float4 w1 = *reinterpret_cast<const float4*>(&w_out[o * 64 + cg * 8 + 4]);
    uint4 wv = make_uint4(pack2(w0.x, w0.y), pack2(w0.z, w0.w), pack2(w1.x, w1.y), pack2(w1.z, w1.w));
    *reinterpret_cast<uint4*>(sm + W_OFF + o * 128 + ((cg * 16) ^ ((o & 7) << 4))) = wv;
  }
  __syncthreads();

  int mtC = w & 3, ntc = (w >> 2) * 2;
  f32x4 accC[2];
  accC[0] = (f32x4){0.f, 0.f, 0.f, 0.f};
  accC[1] = (f32x4){0.f, 0.f, 0.f, 0.f};
  {
    int arow = mtC * 16 + lr;
#pragma unroll
    for (int kt = 0; kt < 2; ++kt) {
      bf16x8 af = *reinterpret_cast<const bf16x8*>(sm + W_OFF + arow * 128 + ((kt * 64 + lk * 16) ^ ((arow & 7) << 4)));
#pragma unroll
      for (int j = 0; j < 2; ++j) {
        int brow = (ntc + j) * 16 + lr;
        bf16x8 bfv = *reinterpret_cast<const bf16x8*>(sm + FOLD_OFF + brow * 128 + ((kt * 64 + lk * 16) ^ ((brow & 7) << 4)));
        accC[j] = __builtin_amdgcn_mfma_f32_16x16x32_bf16(af, bfv, accC[j], 0, 0, 0);
      }
    }
  }
  {
    int o = mtC * 16 + lk * 4;
    float4 bo = *reinterpret_cast<const float4*>(&b_out[o]);
#pragma unroll
    for (int j = 0; j < 2; ++j) {
      int n = (ntc + j) * 16 + lr;
      int pos = n >> 2, tau = n & 3;
      int hw = (y0 + (pos >> 2)) * HH + x0 + (pos & 3);
      uint2 v;
      v.x = pack2(accC[j].x + bo.x, accC[j].y + bo.y);
      v.y = pack2(accC[j].z + bo.z, accC[j].w + bo.w);
      *reinterpret_cast<uint2*>(&pre[(((size_t)b * 4 + tau) * HWD + hw) * 64 + o]) = v;
    }
  }
}

// ---------------- K3: per-channel sum / sumsq of preBN (vectorized, 392 blocks) ----------------
__global__ __launch_bounds__(256) void k_stats(const u16* __restrict__ pre, float* __restrict__ stats) {
  __shared__ float rs[8][64], qs[8][64];
  int tid = threadIdx.x;
  int og = tid & 31, pg = tid >> 5;
  const u32* p32 = reinterpret_cast<const u32*>(pre);
  size_t base = (size_t)blockIdx.x * 256 + pg * 32;
  float s0 = 0.f, s1 = 0.f, q0 = 0.f, q1 = 0.f;
#pragma unroll 4
  for (int j = 0; j < 32; ++j) {
    u32 v = p32[(base + j) * 32 + og];
    float a = bf_lo(v), c = bf_hi(v);
    s0 += a; q0 += a * a;
    s1 += c; q1 += c * c;
  }
  rs[pg][og * 2] = s0; rs[pg][og * 2 + 1] = s1;
  qs[pg][og * 2] = q0; qs[pg][og * 2 + 1] = q1;
  __syncthreads();
  if (tid < 64) {
    float ts = 0.f, tq = 0.f;
#pragma unroll
    for (int g = 0; g < 8; ++g) { ts += rs[g][tid]; tq += qs[g][tid]; }
    atomicAdd(&stats[tid], ts);
    atomicAdd(&stats[64 + tid], tq);
  }
}

// ---------------- K4: BN finalize + residual ----------------
__global__ __launch_bounds__(256) void k_final(const float* __restrict__ x, const u16* __restrict__ pre,
                                               const float* __restrict__ stats,
                                               const float* __restrict__ gamma,
                                               const float* __restrict__ beta,
                                               float* __restrict__ out) {
  __shared__ u16 pre_s[64][66];
  int bi = blockIdx.x;
  int bt = bi / 49, ck = bi % 49;
  int b = bt >> 2, t = bt & 3;
  int hw0 = ck * 64;
  int tid = threadIdx.x;
  const u32* src = reinterpret_cast<const u32*>(pre) + ((size_t)bt * HWD + hw0) * 32;
  for (int task = tid; task < 2048; task += 256) {
    int p = task >> 5, cu = task & 31;
    *reinterpret_cast<u32*>(&pre_s[p][cu * 2]) = src[p * 32 + cu];
  }
  __syncthreads();
  int cg = tid >> 6, pl = tid & 63;
  int hw = hw0 + pl;
  const float invN = 1.f / NTOT;
  for (int i = 0; i < 16; ++i) {
    int c = cg * 16 + i;
    float mu = stats[c] * invN;
    float var = stats[64 + c] * invN - mu * mu;
    float scv = rsqrtf(var + 1e-5f) * gamma[c];
    float sh = beta[c] - mu * scv;
    float v = bf16u(pre_s[pl][c]);
    size_t oi = ((size_t)(b * 64 + c) * 4 + t) * HWD + hw;
    out[oi] = x[oi] + v * scv + sh;
  }
}

extern "C" void kernel_launch(void* const* d_in, const int* in_sizes, int n_in,
                              void* d_out, int out_size, void* d_ws, size_t ws_size,
                              hipStream_t stream) {
  const float* x = (const float*)d_in[0];
  const float* w_in = (const float*)d_in[1];
  const float* b_in = (const float*)d_in[2];
  const float* w_out = (const float*)d_in[3];
  const float* b_out = (const float*)d_in[4];
  const float* gamma = (const float*)d_in[5];
  const float* beta = (const float*)d_in[6];
  float* out = (float*)d_out;

  const size_t NE = (size_t)BB * TT * HWD * 64;
  u16* th = (u16*)d_ws;
  u16* ph = th + NE;
  u16* g2 = ph + NE;
  u16* pre = g2 + NE;
  float* stats = (float*)((char*)d_ws + 4 * NE * sizeof(u16));

  k_conv_in<<<dim3(BB * TT * 49), dim3(256), 0, stream>>>(x, w_in, b_in, th, ph, g2, stats);
  k_attn<<<dim3(BB * 196), dim3(512), 0, stream>>>(th, ph, g2, w_out, b_out, pre);
  k_stats<<<dim3(392), dim3(256), 0, stream>>>(pre, stats);
  k_final<<<dim3(BB * TT * 49), dim3(256), 0, stream>>>(x, pre, stats, gamma, beta, out);
}

// Round 5
// 92.251 us; speedup vs baseline: 3.3236x; 1.0135x over previous
//
#include <hip/hip_runtime.h>

// LocalAttention collapsed form, all-MFMA edition.
// folded[c,t,Y] = (1/36) sum_{c'} theta[c',t,Y] * sum_d cnt(d,Y) sum_r phi[c',r,Y+d]*g[c,r,Y+d]
// K1: conv_in as bf16 MFMA GEMM; K2: attention+fold+conv_out MFMA with XCD-chunked blocks
//     (each XCD owns one b -> halo re-reads are L2 hits) + fused BN-stats reduction.
// ws: theta/phi (pos-major), g (channel-major), preBN bf16 + 128 f32 stats.

typedef unsigned short u16;
typedef unsigned int u32;
using f32x4 = __attribute__((ext_vector_type(4))) float;
using bf16x8 = __attribute__((ext_vector_type(8))) short;

#define BB 8
#define TT 4
#define HH 56
#define HWD 3136
#define NTOT 100352.0f

__device__ __forceinline__ float bf_lo(u32 u) { return __uint_as_float(u << 16); }
__device__ __forceinline__ float bf_hi(u32 u) { return __uint_as_float(u & 0xffff0000u); }
__device__ __forceinline__ float bf16u(u16 u) { return __uint_as_float(((u32)u) << 16); }
__device__ __forceinline__ u16 f2bf(float f) {
  u32 u = __float_as_uint(f);
  u32 r = (u + 0x7fffu + ((u >> 16) & 1u)) >> 16;
  return (u16)r;
}
__device__ __forceinline__ u32 pack2(float a, float b) {
  return (u32)f2bf(a) | ((u32)f2bf(b) << 16);
}
__device__ __forceinline__ int imax(int a, int b) { return a > b ? a : b; }
__device__ __forceinline__ int imin(int a, int b) { return a < b ? a : b; }
__device__ __forceinline__ float cntf(int d, int p) {
  int lo = imax(-1, imax(-1 - d, p - (HH - 1)));
  int hi = imin(1, imin(1 - d, p));
  int n = hi - lo + 1;
  return n > 0 ? (float)n : 0.f;
}

// ---------------- K1: conv_in as bf16 MFMA GEMM ----------------
#define K1_XOFF 24576
__global__ __launch_bounds__(256, 4) void k_conv_in(const float* __restrict__ x,
                                                    const float* __restrict__ w_in,
                                                    const float* __restrict__ b_in,
                                                    u16* __restrict__ th, u16* __restrict__ ph,
                                                    u16* __restrict__ g2, float* __restrict__ stats) {
  __shared__ __align__(16) char sm[24576 + 8192];
  if (blockIdx.x == 0 && threadIdx.x < 128) stats[threadIdx.x] = 0.f;
  int bt = blockIdx.x / 49, chunk = blockIdx.x % 49;
  int b = bt >> 2, t = bt & 3;
  int p0 = chunk * 64;
  int tid = threadIdx.x;

#pragma unroll
  for (int it = 0; it < 12; ++it) {
    int task = it * 256 + tid;
    int o = task >> 4, c4 = (task & 15) * 4;
    float4 wv = *reinterpret_cast<const float4*>(&w_in[o * 64 + c4]);
    uint2 pv;
    pv.x = pack2(wv.x, wv.y);
    pv.y = pack2(wv.z, wv.w);
    *reinterpret_cast<uint2*>(sm + o * 128 + ((c4 * 2) ^ ((o & 7) << 4))) = pv;
  }
  const float* xb = x + ((size_t)b * 256 + t) * HWD + p0;
#pragma unroll
  for (int it = 0; it < 2; ++it) {
    int task = it * 256 + tid;
    int cp = task >> 4, p4 = task & 15;
    int c0 = cp * 2;
    float4 fa = *reinterpret_cast<const float4*>(&xb[(size_t)c0 * 4 * HWD + p4 * 4]);
    float4 fb = *reinterpret_cast<const float4*>(&xb[(size_t)(c0 + 1) * 4 * HWD + p4 * 4]);
    float va[4] = {fa.x, fa.y, fa.z, fa.w}, vb[4] = {fb.x, fb.y, fb.z, fb.w};
#pragma unroll
    for (int j = 0; j < 4; ++j) {
      int p = p4 * 4 + j;
      int slot = (p & 7) ^ ((p >> 2) & 7);
      *reinterpret_cast<u32*>(sm + K1_XOFF + p * 128 + ((c0 * 2) ^ (slot << 4))) = pack2(va[j], vb[j]);
    }
  }
  __syncthreads();

  int w = tid >> 6, lane = tid & 63, lr = lane & 15, lk = lane >> 4;
  f32x4 acc[3][4];
#pragma unroll
  for (int i = 0; i < 3; ++i)
#pragma unroll
    for (int n = 0; n < 4; ++n) acc[i][n] = (f32x4){0.f, 0.f, 0.f, 0.f};

#pragma unroll
  for (int kt = 0; kt < 2; ++kt) {
    bf16x8 af[3], bfr[4];
#pragma unroll
    for (int i = 0; i < 3; ++i) {
      int arow = (w * 3 + i) * 16 + lr;
      af[i] = *reinterpret_cast<const bf16x8*>(sm + arow * 128 + ((kt * 64 + lk * 16) ^ ((arow & 7) << 4)));
    }
#pragma unroll
    for (int n = 0; n < 4; ++n) {
      int brow = n * 16 + lr;
      int slot = (brow & 7) ^ ((brow >> 2) & 7);
      bfr[n] = *reinterpret_cast<const bf16x8*>(sm + K1_XOFF + brow * 128 + ((kt * 64 + lk * 16) ^ (slot << 4)));
    }
#pragma unroll
    for (int i = 0; i < 3; ++i)
#pragma unroll
      for (int n = 0; n < 4; ++n)
        acc[i][n] = __builtin_amdgcn_mfma_f32_16x16x32_bf16(af[i], bfr[n], acc[i][n], 0, 0, 0);
  }

#pragma unroll
  for (int i = 0; i < 3; ++i) {
    int mt = w * 3 + i;
    int ob = mt * 16 + lk * 4;
    int gsel = ob >> 6, o = ob & 63;
    float4 bv = *reinterpret_cast<const float4*>(&b_in[ob]);
#pragma unroll
    for (int n = 0; n < 4; ++n) {
      int p = p0 + n * 16 + lr;
      f32x4 a = acc[i][n];
      if (gsel < 2) {
        u16* og = gsel == 0 ? th : ph;
        uint2 v;
        v.x = pack2(a.x + bv.x, a.y + bv.y);
        v.y = pack2(a.z + bv.z, a.w + bv.w);
        *reinterpret_cast<uint2*>(&og[((size_t)bt * HWD + p) * 64 + o]) = v;
      } else {
        float aa[4] = {a.x, a.y, a.z, a.w};
        float bb[4] = {bv.x, bv.y, bv.z, bv.w};
#pragma unroll
        for (int r = 0; r < 4; ++r)
          g2[(((size_t)b * 64 + o + r) * 4 + t) * HWD + p] = f2bf(aa[r] + bb[r]);
      }
    }
  }
}

// ---------------- K2: MFMA attention (+fused BN stats) ----------------
#define PH_OFF 0
#define AS_OFF 0
#define G_OFF 32768
#define W_OFF 32768
#define TH_OFF 65536
#define FOLD_OFF 65536
#define TAB_OFF 73728
#define STAT_OFF 73984

__global__ __launch_bounds__(512, 4) void k_attn(const u16* __restrict__ th, const u16* __restrict__ ph,
                                                 const u16* __restrict__ g2,
                                                 const float* __restrict__ w_out,
                                                 const float* __restrict__ b_out,
                                                 u16* __restrict__ pre, float* __restrict__ stats) {
  __shared__ __align__(16) char sm[74496];

  // XCD-chunked block swizzle: 1568 = 8*196, so XCD k owns image b=k entirely ->
  // halo-sharing neighbor tiles hit the same per-XCD L2.
  int bi0 = blockIdx.x;
  int bi = (bi0 & 7) * 196 + (bi0 >> 3);
  int b = bi / 196, tile = bi % 196;
  int ty = tile / 14, tx = tile % 14;
  int y0 = ty * 4, x0 = tx * 4;
  int tid = threadIdx.x;
  int w = tid >> 6, lane = tid & 63;
  int lr = lane & 15, lk = lane >> 4;

  if (tid < 128) reinterpret_cast<float*>(sm + STAT_OFF)[tid] = 0.f;

  for (int task = tid; task < 2048; task += 512) {
    int row = task >> 3, ch = task & 7;
    int rho = row >> 6, Z = row & 63, zy = Z >> 3, zx = Z & 7;
    int Y = y0 - 2 + zy, X = x0 - 2 + zx;
    uint4 v = make_uint4(0, 0, 0, 0);
    if ((unsigned)Y < HH && (unsigned)X < HH)
      v = *reinterpret_cast<const uint4*>(&ph[(((size_t)b * 4 + rho) * HWD + Y * HH + X) * 64 + ch * 8]);
    *reinterpret_cast<uint4*>(sm + PH_OFF + row * 128 + ((ch * 16) ^ ((row & 7) << 4))) = v;
  }
  {
    int row = tid >> 3, ch = tid & 7;
    int pos = row >> 2, tau = row & 3;
    int Y = y0 + (pos >> 2), X = x0 + (pos & 3);
    uint4 v = *reinterpret_cast<const uint4*>(&th[(((size_t)b * 4 + tau) * HWD + Y * HH + X) * 64 + ch * 8]);
    *reinterpret_cast<uint4*>(sm + TH_OFF + row * 128 + ((ch * 16) ^ ((row & 7) << 4))) = v;
  }
  for (int task = tid; task < 2048; task += 512) {
    int c = task >> 5, rho = (task >> 3) & 3, zy = task & 7;
    int Y = y0 - 2 + zy;
    u32 pv[4] = {0, 0, 0, 0};
    if ((unsigned)Y < HH) {
      size_t rowbase = (((size_t)b * 64 + c) * 4 + rho) * HWD + (size_t)Y * HH;
      int xb = x0 - 2;
#pragma unroll
      for (int j = 0; j < 4; ++j) {
        int X = xb + 2 * j;
        if ((unsigned)X < HH) pv[j] = *reinterpret_cast<const u32*>(&g2[rowbase + X]);
      }
    }
    uint4 v = make_uint4(pv[0], pv[1], pv[2], pv[3]);
    *reinterpret_cast<uint4*>(sm + G_OFF + c * 512 + ((16 * (rho * 8 + zy)) ^ ((c & 7) << 4))) = v;
  }
  if (tid < 32) {
    int zy = tid >> 2, py = tid & 3;
    reinterpret_cast<float*>(sm + TAB_OFF)[tid] = cntf(zy - 2 - py, y0 + py) * (1.f / 36.f);
  } else if (tid < 64) {
    int i = tid - 32;
    int zx = i >> 2, px = i & 3;
    reinterpret_cast<float*>(sm + TAB_OFF + 128)[i] = cntf(zx - 2 - px, x0 + px);
  }
  __syncthreads();

  bf16x8 tb[4][2];
#pragma unroll
  for (int nt = 0; nt < 4; ++nt)
#pragma unroll
    for (int kt = 0; kt < 2; ++kt) {
      int row = nt * 16 + lr;
      tb[nt][kt] = *reinterpret_cast<const bf16x8*>(sm + TH_OFF + row * 128 + ((kt * 64 + lk * 16) ^ ((row & 7) << 4)));
    }
  f32x4 accA[2][4];
#pragma unroll
  for (int mi = 0; mi < 2; ++mi)
#pragma unroll
    for (int nt = 0; nt < 4; ++nt) accA[mi][nt] = (f32x4){0.f, 0.f, 0.f, 0.f};
#pragma unroll
  for (int mi = 0; mi < 2; ++mi) {
    int mrow = (w * 2 + mi) * 16 + lr;
#pragma unroll
    for (int kt = 0; kt < 2; ++kt) {
      bf16x8 af = *reinterpret_cast<const bf16x8*>(sm + PH_OFF + mrow * 128 + ((kt * 64 + lk * 16) ^ ((mrow & 7) << 4)));
#pragma unroll
      for (int nt = 0; nt < 4; ++nt)
        accA[mi][nt] = __builtin_amdgcn_mfma_f32_16x16x32_bf16(af, tb[nt][kt], accA[mi][nt], 0, 0, 0);
    }
  }
  __syncthreads();

  {
    const float* cyt = reinterpret_cast<const float*>(sm + TAB_OFF);
    const float* cxt = reinterpret_cast<const float*>(sm + TAB_OFF + 128);
#pragma unroll
    for (int mi = 0; mi < 2; ++mi) {
      int mbase = (w * 2 + mi) * 16 + lk * 4;
#pragma unroll
      for (int nt = 0; nt < 4; ++nt) {
        int n = nt * 16 + lr;
        int pos = n >> 2;
        int py = pos >> 2, px = pos & 3;
        float sc[4];
#pragma unroll
        for (int r = 0; r < 4; ++r) {
          int Z = (mbase + r) & 63;
          sc[r] = cyt[(Z >> 3) * 4 + py] * cxt[(Z & 7) * 4 + px];
        }
        f32x4 a = accA[mi][nt];
        uint2 vv;
        vv.x = pack2(a.x * sc[0], a.y * sc[1]);
        vv.y = pack2(a.z * sc[2], a.w * sc[3]);
        *reinterpret_cast<uint2*>(sm + AS_OFF + n * 512 + ((mbase * 2) ^ ((n & 7) << 4))) = vv;
      }
    }
  }
  __syncthreads();

  int mtB = w & 3, ntb = (w >> 2) * 2;
  f32x4 accB[2];
  accB[0] = (f32x4){0.f, 0.f, 0.f, 0.f};
  accB[1] = (f32x4){0.f, 0.f, 0.f, 0.f};
  {
    int arow = mtB * 16 + lr;
#pragma unroll
    for (int kt = 0; kt < 8; ++kt) {
      bf16x8 af = *reinterpret_cast<const bf16x8*>(sm + AS_OFF + arow * 512 + ((kt * 64 + lk * 16) ^ ((arow & 7) << 4)));
#pragma unroll
      for (int j = 0; j < 2; ++j) {
        int brow = (ntb + j) * 16 + lr;
        bf16x8 bfv = *reinterpret_cast<const bf16x8*>(sm + G_OFF + brow * 512 + ((kt * 64 + lk * 16) ^ ((brow & 7) << 4)));
        accB[j] = __builtin_amdgcn_mfma_f32_16x16x32_bf16(af, bfv, accB[j], 0, 0, 0);
      }
    }
  }
  __syncthreads();

#pragma unroll
  for (int j = 0; j < 2; ++j) {
    int n = (ntb + j) * 16 + lr;
#pragma unroll
    for (int r = 0; r < 4; ++r) {
      int m = mtB * 16 + lk * 4 + r;
      *reinterpret_cast<u16*>(sm + FOLD_OFF + m * 128 + ((n * 2) ^ ((m & 7) << 4))) = f2bf(accB[j][r]);
    }
  }
  {
    int o = tid >> 3, cg = tid & 7;
    float4 w0 = *reinterpret_cast<const float4*>(&w_out[o * 64 + cg * 8]);
    float4 w1 = *reinterpret_cast<const float4*>(&w_out[o * 64 + cg * 8 + 4]);
    uint4 wv = make_uint4(pack2(w0.x, w0.y), pack2(w0.z, w0.w), pack2(w1.x, w1.y), pack2(w1.z, w1.w));
    *reinterpret_cast<uint4*>(sm + W_OFF + o * 128 + ((cg * 16) ^ ((o & 7) << 4))) = wv;
  }
  __syncthreads();

  int mtC = w & 3, ntc = (w >> 2) * 2;
  f32x4 accC[2];
  accC[0] = (f32x4){0.f, 0.f, 0.f, 0.f};
  accC[1] = (f32x4){0.f, 0.f, 0.f, 0.f};
  {
    int arow = mtC * 16 + lr;
#pragma unroll
    for (int kt = 0; kt < 2; ++kt) {
      bf16x8 af = *reinterpret_cast<const bf16x8*>(sm + W_OFF + arow * 128 + ((kt * 64 + lk * 16) ^ ((arow & 7) << 4)));
#pragma unroll
      for (int j = 0; j < 2; ++j) {
        int brow = (ntc + j) * 16 + lr;
        bf16x8 bfv = *reinterpret_cast<const bf16x8*>(sm + FOLD_OFF + brow * 128 + ((kt * 64 + lk * 16) ^ ((brow & 7) << 4)));
        accC[j] = __builtin_amdgcn_mfma_f32_16x16x32_bf16(af, bfv, accC[j], 0, 0, 0);
      }
    }
  }
  {
    int o4 = mtC * 16 + lk * 4;
    float4 bo = *reinterpret_cast<const float4*>(&b_out[o4]);
    float bof[4] = {bo.x, bo.y, bo.z, bo.w};
    float sv[4] = {0.f, 0.f, 0.f, 0.f}, qv[4] = {0.f, 0.f, 0.f, 0.f};
#pragma unroll
    for (int j = 0; j < 2; ++j) {
      int n = (ntc + j) * 16 + lr;
      int pos = n >> 2, tau = n & 3;
      int hw = (y0 + (pos >> 2)) * HH + x0 + (pos & 3);
      float v0 = accC[j].x + bof[0], v1 = accC[j].y + bof[1];
      float v2 = accC[j].z + bof[2], v3 = accC[j].w + bof[3];
      uint2 v;
      v.x = pack2(v0, v1);
      v.y = pack2(v2, v3);
      *reinterpret_cast<uint2*>(&pre[(((size_t)b * 4 + tau) * HWD + hw) * 64 + o4]) = v;
      sv[0] += v0; qv[0] += v0 * v0;
      sv[1] += v1; qv[1] += v1 * v1;
      sv[2] += v2; qv[2] += v2 * v2;
      sv[3] += v3; qv[3] += v3 * v3;
    }
    // reduce over the 16 lr-lanes (same o-set per lk)
#pragma unroll
    for (int off = 1; off < 16; off <<= 1) {
#pragma unroll
      for (int r = 0; r < 4; ++r) {
        sv[r] += __shfl_xor(sv[r], off);
        qv[r] += __shfl_xor(qv[r], off);
      }
    }
    if (lr == 0) {
      float* st = reinterpret_cast<float*>(sm + STAT_OFF);
#pragma unroll
      for (int r = 0; r < 4; ++r) {
        atomicAdd(&st[o4 + r], sv[r]);
        atomicAdd(&st[64 + o4 + r], qv[r]);
      }
    }
  }
  __syncthreads();
  if (tid < 128) atomicAdd(&stats[tid], reinterpret_cast<float*>(sm + STAT_OFF)[tid]);
}

// ---------------- K4: BN finalize + residual ----------------
__global__ __launch_bounds__(256) void k_final(const float* __restrict__ x, const u16* __restrict__ pre,
                                               const float* __restrict__ stats,
                                               const float* __restrict__ gamma,
                                               const float* __restrict__ beta,
                                               float* __restrict__ out) {
  __shared__ u16 pre_s[64][66];
  int bi = blockIdx.x;
  int bt = bi / 49, ck = bi % 49;
  int b = bt >> 2, t = bt & 3;
  int hw0 = ck * 64;
  int tid = threadIdx.x;
  const u32* src = reinterpret_cast<const u32*>(pre) + ((size_t)bt * HWD + hw0) * 32;
  for (int task = tid; task < 2048; task += 256) {
    int p = task >> 5, cu = task & 31;
    *reinterpret_cast<u32*>(&pre_s[p][cu * 2]) = src[p * 32 + cu];
  }
  __syncthreads();
  int cg = tid >> 6, pl = tid & 63;
  int hw = hw0 + pl;
  const float invN = 1.f / NTOT;
  for (int i = 0; i < 16; ++i) {
    int c = cg * 16 + i;
    float mu = stats[c] * invN;
    float var = stats[64 + c] * invN - mu * mu;
    float scv = rsqrtf(var + 1e-5f) * gamma[c];
    float sh = beta[c] - mu * scv;
    float v = bf16u(pre_s[pl][c]);
    size_t oi = ((size_t)(b * 64 + c) * 4 + t) * HWD + hw;
    out[oi] = x[oi] + v * scv + sh;
  }
}

extern "C" void kernel_launch(void* const* d_in, const int* in_sizes, int n_in,
                              void* d_out, int out_size, void* d_ws, size_t ws_size,
                              hipStream_t stream) {
  const float* x = (const float*)d_in[0];
  const float* w_in = (const float*)d_in[1];
  const float* b_in = (const float*)d_in[2];
  const float* w_out = (const float*)d_in[3];
  const float* b_out = (const float*)d_in[4];
  const float* gamma = (const float*)d_in[5];
  const float* beta = (const float*)d_in[6];
  float* out = (float*)d_out;

  const size_t NE = (size_t)BB * TT * HWD * 64;
  u16* th = (u16*)d_ws;
  u16* ph = th + NE;
  u16* g2 = ph + NE;
  u16* pre = g2 + NE;
  float* stats = (float*)((char*)d_ws + 4 * NE * sizeof(u16));

  k_conv_in<<<dim3(BB * TT * 49), dim3(256), 0, stream>>>(x, w_in, b_in, th, ph, g2, stats);
  k_attn<<<dim3(BB * 196), dim3(512), 0, stream>>>(th, ph, g2, w_out, b_out, pre, stats);
  k_final<<<dim3(BB * TT * 49), dim3(256), 0, stream>>>(x, pre, stats, gamma, beta, out);
}